// Round 5
// baseline (425.386 us; speedup 1.0000x reference)
//
#include <hip/hip_runtime.h>

// Residual_feature: three chained depthwise convs on (64,3,512,512) fp32.
//   edge     = conv(x, K1)        K1 inner 3x3 = [-1,2,-1; 2,4,2; -1,2,-1]
//   texture  = conv(edge, K2)     K2 = -(l^T l) - 2*(m^T m), l=[1,-2,2,-2,1], m=[0,1,-2,1,0]
//   residual = conv(texture, K3)  K3 = horizontal [1,-2,1]
// Staged zero padding: intermediates are zero outside the image at each stage
// (E rows zeroed at completion when row index outside [0,H)).
//
// R4 post-mortem: 3 different structures all ~147us, VALUBusy ~35%, HBM ~31%,
//   occupancy invariant to grid size -> NOT wave-count-bound, NOT VALU-bound.
//   Little's law: ~1 row (2KB) in flight per wave caps chip at ~2.5 TB/s.
// R5 (this): MLP restructure. Per group: batch-issue 4 row loads (8KB/wave in
//   flight, 4x deeper), branchless clamped loads so all dwordx4 issue before
//   the first waitcnt; fold 4 E rows (ping-pong banks, no copies); emit 4
//   output rows. launch_bounds(256,3): VGPR cap ~168, est peak ~140.

#define H 512
#define W 512
#define RS 16          // output rows per wave-strip
#define STRIPS (H/RS)  // 32
#define LOG2_STRIPS 5

typedef float v4f __attribute__((ext_vector_type(4)));

__device__ __forceinline__ void load_row(const float* __restrict__ xp, int r, int cb, int lane,
                                         float v[8], float& lo, float& hi) {
    int rc = r; if (rc < 0) rc = 0; if (rc > H - 1) rc = H - 1;   // clamp: always-legal addr
    const float* rp = xp + rc * W;
    v4f a = *(const v4f*)(rp + cb);
    v4f b = *(const v4f*)(rp + cb + 4);
    float l = rp[(lane == 0)  ? 0       : cb - 1];
    float h = rp[(lane == 63) ? W - 1   : cb + 8];
    const bool ok = (r >= 0) && (r < H);
    v[0] = ok ? a.x : 0.f; v[1] = ok ? a.y : 0.f; v[2] = ok ? a.z : 0.f; v[3] = ok ? a.w : 0.f;
    v[4] = ok ? b.x : 0.f; v[5] = ok ? b.y : 0.f; v[6] = ok ? b.z : 0.f; v[7] = ok ? b.w : 0.f;
    lo = (ok && lane > 0)  ? l : 0.f;   // x zero-pad at col -1
    hi = (ok && lane < 63) ? h : 0.f;   // x zero-pad at col 512
}

// Fold x row r into the vertical-K1 accumulators; completes E[r-1] into Eout.
// h1 = [-1,2,-1]*x (outer K1 rows), h2 = [2,4,2]*x (center row).
#define FOLD(xv, xl, xh, r, Eout, KEEP)                                   \
  {                                                                       \
    const bool eok = ((r) - 1 >= 0) && ((r) - 1 < H);                     \
    _Pragma("unroll")                                                     \
    for (int j = 0; j < 8; ++j) {                                         \
      float xm = (j >= 1) ? xv[j-1] : xl;                                 \
      float xq = (j <= 6) ? xv[j+1] : xh;                                 \
      float h1 = 2.f*xv[j] - xm - xq;                                     \
      float h2 = 8.f*xv[j] - 2.f*h1;                                      \
      if (KEEP) Eout[j] = eok ? (a0[j] + h1) : 0.f;                       \
      a0[j] = a1[j] + h2;                                                 \
      a1[j] = h1;                                                         \
    }                                                                     \
  }

// Emit output row p from E rows p-2..p+2 (the five arrays, in order).
#define OUTROW(p, Em2, Em1, Ez, Ep1, Ep2)                                 \
  {                                                                       \
    float A[8], B[8];                                                     \
    _Pragma("unroll")                                                     \
    for (int j = 0; j < 8; ++j) {                                         \
      A[j] = Em2[j] - 2.f*Em1[j] + 2.f*Ez[j] - 2.f*Ep1[j] + Ep2[j];       \
      B[j] = Em1[j] - 2.f*Ez[j] + Ep1[j];                                 \
    }                                                                     \
    float al1 = __shfl_up(A[7], 1, 64);                                   \
    float al2 = __shfl_up(A[6], 1, 64);                                   \
    float ah1 = __shfl_down(A[0], 1, 64);                                 \
    float ah2 = __shfl_down(A[1], 1, 64);                                 \
    float bl  = __shfl_up(B[7], 1, 64);                                   \
    float bh  = __shfl_down(B[0], 1, 64);                                 \
    if (lane == 0)  { al1 = 0.f; al2 = 0.f; bl = 0.f; }                   \
    if (lane == 63) { ah1 = 0.f; ah2 = 0.f; bh = 0.f; }                   \
    float T[8];                                                           \
    _Pragma("unroll")                                                     \
    for (int j = 0; j < 8; ++j) {                                         \
      float am2 = (j >= 2) ? A[j-2] : ((j == 1) ? al1 : al2);             \
      float am1 = (j >= 1) ? A[j-1] : al1;                                \
      float ap1 = (j <= 6) ? A[j+1] : ah1;                                \
      float ap2 = (j <= 5) ? A[j+2] : ((j == 6) ? ah1 : ah2);             \
      float bm  = (j >= 1) ? B[j-1] : bl;                                 \
      float bp  = (j <= 6) ? B[j+1] : bh;                                 \
      float lt = am2 - 2.f*am1 + 2.f*A[j] - 2.f*ap1 + ap2;                \
      float mt = bm - 2.f*B[j] + bp;                                      \
      T[j] = -lt - 2.f*mt;                                                \
    }                                                                     \
    float tl = __shfl_up(T[7], 1, 64);                                    \
    float th = __shfl_down(T[0], 1, 64);                                  \
    if (lane == 0)  tl = 0.f;                                             \
    if (lane == 63) th = 0.f;                                             \
    float Rr[8];                                                          \
    _Pragma("unroll")                                                     \
    for (int j = 0; j < 8; ++j) {                                         \
      float tm = (j >= 1) ? T[j-1] : tl;                                  \
      float tp = (j <= 6) ? T[j+1] : th;                                  \
      Rr[j] = tm - 2.f*T[j] + tp;                                         \
    }                                                                     \
    v4f o0 = { Rr[0], Rr[1], Rr[2], Rr[3] };                              \
    v4f o1 = { Rr[4], Rr[5], Rr[6], Rr[7] };                              \
    float* dst = op + (p) * W + cb;                                       \
    __builtin_nontemporal_store(o0, (v4f*)(dst));                         \
    __builtin_nontemporal_store(o1, (v4f*)(dst + 4));                     \
  }

// One group: batch-load x rows P+3..P+6, fold -> E[P+2..P+5] into Nx bank,
// emit output rows P..P+3 from (Ox = E[P-2..P+1], Nx).
#define GROUP(P, Oa, Ob, Oc, Od, Na, Nb, Nc, Nd)                          \
  {                                                                       \
    float xv0[8], xv1[8], xv2[8], xv3[8];                                 \
    float xl0, xh0, xl1, xh1, xl2, xh2, xl3, xh3;                         \
    load_row(xp, (P)+3, cb, lane, xv0, xl0, xh0);                         \
    load_row(xp, (P)+4, cb, lane, xv1, xl1, xh1);                         \
    load_row(xp, (P)+5, cb, lane, xv2, xl2, xh2);                         \
    load_row(xp, (P)+6, cb, lane, xv3, xl3, xh3);                         \
    FOLD(xv0, xl0, xh0, (P)+3, Na, true);                                 \
    FOLD(xv1, xl1, xh1, (P)+4, Nb, true);                                 \
    FOLD(xv2, xl2, xh2, (P)+5, Nc, true);                                 \
    FOLD(xv3, xl3, xh3, (P)+6, Nd, true);                                 \
    OUTROW((P),   Oa, Ob, Oc, Od, Na);                                    \
    OUTROW((P)+1, Ob, Oc, Od, Na, Nb);                                    \
    OUTROW((P)+2, Oc, Od, Na, Nb, Nc);                                    \
    OUTROW((P)+3, Od, Na, Nb, Nc, Nd);                                    \
  }

__global__ __launch_bounds__(256, 3)
void resid_kernel(const float* __restrict__ x, float* __restrict__ out) {
    const int lane  = threadIdx.x & 63;
    const int wid   = (blockIdx.x << 2) | (threadIdx.x >> 6);
    const int plane = wid >> LOG2_STRIPS;  // wid / STRIPS
    const int strip = wid & (STRIPS - 1);
    const int r0    = strip * RS;
    const int cb    = lane << 3;           // 8 contiguous cols per lane

    const float* __restrict__ xp = x + (size_t)plane * (H * W);
    float* __restrict__ op = out + (size_t)plane * (H * W);

    // vertical-K1 rolling partials: a0 = E[next] partial, a1 = E[next+1] partial
    float a0[8], a1[8];
    #pragma unroll
    for (int j = 0; j < 8; ++j) { a0[j] = 0.f; a1[j] = 0.f; }

    // ping-pong E banks (4 rows each)
    float O0[8], O1[8], O2[8], O3[8];
    float N0[8], N1[8], N2[8], N3[8];

    // ---- prologue: rows r0-3 .. r0+2 (6 loads batched), fill O = E[r0-2..r0+1]
    {
        float pv0[8], pv1[8], pv2[8], pv3[8], pv4[8], pv5[8];
        float pl0, ph0, pl1, ph1, pl2, ph2, pl3, ph3, pl4, ph4, pl5, ph5;
        load_row(xp, r0-3, cb, lane, pv0, pl0, ph0);
        load_row(xp, r0-2, cb, lane, pv1, pl1, ph1);
        load_row(xp, r0-1, cb, lane, pv2, pl2, ph2);
        load_row(xp, r0,   cb, lane, pv3, pl3, ph3);
        load_row(xp, r0+1, cb, lane, pv4, pl4, ph4);
        load_row(xp, r0+2, cb, lane, pv5, pl5, ph5);
        FOLD(pv0, pl0, ph0, r0-3, O0, false);   // completes E[r0-4]: discarded
        FOLD(pv1, pl1, ph1, r0-2, O0, false);   // completes E[r0-3]: discarded
        FOLD(pv2, pl2, ph2, r0-1, O0, true);    // E[r0-2]
        FOLD(pv3, pl3, ph3, r0,   O1, true);    // E[r0-1]
        FOLD(pv4, pl4, ph4, r0+1, O2, true);    // E[r0]
        FOLD(pv5, pl5, ph5, r0+2, O3, true);    // E[r0+1]
    }

    GROUP(r0,      O0, O1, O2, O3, N0, N1, N2, N3);
    GROUP(r0 + 4,  N0, N1, N2, N3, O0, O1, O2, O3);
    GROUP(r0 + 8,  O0, O1, O2, O3, N0, N1, N2, N3);
    GROUP(r0 + 12, N0, N1, N2, N3, O0, O1, O2, O3);
}

extern "C" void kernel_launch(void* const* d_in, const int* in_sizes, int n_in,
                              void* d_out, int out_size, void* d_ws, size_t ws_size,
                              hipStream_t stream) {
    const float* x = (const float*)d_in[0];
    float* out = (float*)d_out;
    // 192 planes * 32 strips = 6144 waves / 4 waves per block = 1536 blocks
    resid_kernel<<<dim3(1536), dim3(256), 0, stream>>>(x, out);
}